// Round 1
// baseline (596.179 us; speedup 1.0000x reference)
//
#include <hip/hip_runtime.h>
#include <math.h>

#define BB 16
#define SS 4096
#define DDIM 512
#define NCODE 256
#define MTOK (BB*SS)              // 65536 tokens

// d_out layout (floats)
#define LOSS_OFF 33554432
#define IDX_OFF  33554433
#define WGT_OFF  33619969

// d_ws layout (floats)
#define WS_LOSS 0                 // 2 floats (sum (x-qu)^2, sum (x-qk)^2)
#define WS_POOL 8                 // 8192 floats (per-b per-d sums)
#define WS_C2   8200              // 256 floats
#define WS_WGT  8464              // 32 floats

__global__ void init_ws(float* ws) {
  int i = blockIdx.x * blockDim.x + threadIdx.x;
  if (i < 8200) ws[i] = 0.f;
}

__global__ void c2_kernel(const float* __restrict__ cb, float* __restrict__ c2) {
  int k = blockIdx.x;
  int t = threadIdx.x;  // 64
  const float4* p = (const float4*)(cb + (size_t)k * DDIM);
  float4 a = p[t * 2], b = p[t * 2 + 1];
  float s = a.x*a.x + a.y*a.y + a.z*a.z + a.w*a.w
          + b.x*b.x + b.y*b.y + b.z*b.z + b.w*b.w;
  for (int m = 1; m <= 32; m <<= 1) s += __shfl_xor(s, m, 64);
  if (t == 0) c2[k] = s;
}

__global__ __launch_bounds__(512) void pool_kernel(const float* __restrict__ x,
                                                   float* __restrict__ pool) {
  int b = blockIdx.x, sc = blockIdx.y, d = threadIdx.x;  // 512 threads = one d each
  const float* p = x + ((size_t)b * SS + (size_t)sc * 256) * DDIM + d;
  float s = 0.f;
  #pragma unroll 8
  for (int i = 0; i < 256; i++) s += p[(size_t)i * DDIM];
  atomicAdd(&pool[b * DDIM + d], s);
}

__global__ __launch_bounds__(256) void selector_kernel(
    const float* __restrict__ poolsum, const float* __restrict__ w1,
    const float* __restrict__ b1, const float* __restrict__ w2,
    const float* __restrict__ b2, float* __restrict__ ws_w,
    float* __restrict__ out) {
  __shared__ float pl[DDIM];
  __shared__ float r0[256], r1[256];
  int b = blockIdx.x, t = threadIdx.x;
  pl[t]       = poolsum[b * DDIM + t]       * (1.f / SS);
  pl[t + 256] = poolsum[b * DDIM + t + 256] * (1.f / SS);
  __syncthreads();
  float h = b1[t];
  for (int d = 0; d < DDIM; d++) h = fmaf(pl[d], w1[d * 256 + t], h);
  h = fmaxf(h, 0.f);
  r0[t] = h * w2[t * 2];
  r1[t] = h * w2[t * 2 + 1];
  __syncthreads();
  for (int s = 128; s > 0; s >>= 1) {
    if (t < s) { r0[t] += r0[t + s]; r1[t] += r1[t + s]; }
    __syncthreads();
  }
  if (t == 0) {
    float l0 = r0[0] + b2[0], l1 = r1[0] + b2[1];
    float mx = fmaxf(l0, l1);
    float e0 = expf(l0 - mx), e1 = expf(l1 - mx);
    float inv = 1.f / (e0 + e1);
    float wa = e0 * inv, wb = e1 * inv;
    ws_w[b * 2] = wa; ws_w[b * 2 + 1] = wb;
    out[WGT_OFF + b * 2] = wa; out[WGT_OFF + b * 2 + 1] = wb;
  }
}

// 64 tokens x 256 codes per block, BK=32, 8x8 register tile per thread.
__global__ __launch_bounds__(256) void gemm_argmin(
    const float* __restrict__ x, const float* __restrict__ cb,
    const float* __restrict__ means, const float* __restrict__ stds,
    const float* __restrict__ c2, float* __restrict__ idx_out) {
  __shared__ float xs[64][36];    // pad 36: float4-aligned rows, conflict-light
  __shared__ float cs[32][257];   // pad 257: conflict-free column scatter + row reads
  int tid = threadIdx.x;
  int tx = tid & 31, ty = tid >> 5;
  size_t token0 = (size_t)blockIdx.x * 64;

  float acc[8][8];
  #pragma unroll
  for (int t = 0; t < 8; t++)
    #pragma unroll
    for (int c = 0; c < 8; c++) acc[t][c] = 0.f;

  for (int kb = 0; kb < DDIM; kb += 32) {
    // stage x tile (64 rows x 32 cols), normalized: (x - mean)/std
    #pragma unroll
    for (int r = 0; r < 2; r++) {
      int i = tid * 2 + r;             // 0..511 float4 slots
      int row = i >> 3, c4 = (i & 7) * 4;
      float4 xv = *(const float4*)(x + (token0 + row) * DDIM + kb + c4);
      float4 mv = *(const float4*)(means + kb + c4);
      float4 sv = *(const float4*)(stds + kb + c4);
      float4 xn;
      xn.x = (xv.x - mv.x) / sv.x; xn.y = (xv.y - mv.y) / sv.y;
      xn.z = (xv.z - mv.z) / sv.z; xn.w = (xv.w - mv.w) / sv.w;
      *(float4*)(&xs[row][c4]) = xn;
    }
    // stage codebook tile transposed: cs[kk][code]
    #pragma unroll
    for (int r = 0; r < 8; r++) {
      int j = tid + 256 * r;           // 0..2047 float4 slots
      int code = j >> 3, k4 = (j & 7) * 4;
      float4 cv = *(const float4*)(cb + (size_t)code * DDIM + kb + k4);
      cs[k4 + 0][code] = cv.x; cs[k4 + 1][code] = cv.y;
      cs[k4 + 2][code] = cv.z; cs[k4 + 3][code] = cv.w;
    }
    __syncthreads();

    float accc[8][8];                  // per-chunk accumulator (pairwise summation:
    #pragma unroll                     //  cuts fp32 dot error ~5x for argmin safety)
    for (int t = 0; t < 8; t++)
      #pragma unroll
      for (int c = 0; c < 8; c++) accc[t][c] = 0.f;

    #pragma unroll 4
    for (int kk = 0; kk < 32; kk++) {
      float a[8], bv[8];
      #pragma unroll
      for (int t = 0; t < 8; t++) a[t] = xs[ty * 8 + t][kk];
      #pragma unroll
      for (int c = 0; c < 8; c++) bv[c] = cs[kk][tx + 32 * c];
      #pragma unroll
      for (int t = 0; t < 8; t++)
        #pragma unroll
        for (int c = 0; c < 8; c++)
          accc[t][c] = fmaf(a[t], bv[c], accc[t][c]);
    }
    #pragma unroll
    for (int t = 0; t < 8; t++)
      #pragma unroll
      for (int c = 0; c < 8; c++) acc[t][c] += accc[t][c];
    __syncthreads();
  }

  float c2v[8];
  #pragma unroll
  for (int c = 0; c < 8; c++) c2v[c] = c2[tx + 32 * c];

  #pragma unroll
  for (int t = 0; t < 8; t++) {
    float bvv = fmaf(-2.f, acc[t][0], c2v[0]);
    int bi = tx;
    #pragma unroll
    for (int c = 1; c < 8; c++) {
      float v = fmaf(-2.f, acc[t][c], c2v[c]);
      int ci = tx + 32 * c;
      if (v < bvv || (v == bvv && ci < bi)) { bvv = v; bi = ci; }
    }
    // reduce across the 32 lanes sharing ty (xor masks stay within half-wave)
    for (int m = 1; m <= 16; m <<= 1) {
      float ov = __shfl_xor(bvv, m, 64);
      int oi = __shfl_xor(bi, m, 64);
      if (ov < bvv || (ov == bvv && oi < bi)) { bvv = ov; bi = oi; }
    }
    if (tx == 0) idx_out[token0 + ty * 8 + t] = (float)bi;
  }
}

__global__ __launch_bounds__(256) void output_kernel(
    const float* __restrict__ x, const float* __restrict__ cb,
    const float* __restrict__ means, const float* __restrict__ stds,
    const float* __restrict__ idx_f, const float* __restrict__ wsel,
    float* __restrict__ out, float* __restrict__ loss_acc) {
  const float step = (float)(2.0 / 7.0);
  float lu = 0.f, lk = 0.f;
  int tid = threadIdx.x;
  size_t stride = (size_t)gridDim.x * blockDim.x;
  size_t total = (size_t)MTOK * 128;   // float4 items
  for (size_t i = (size_t)blockIdx.x * blockDim.x + tid; i < total; i += stride) {
    size_t token = i >> 7;
    int d4 = (int)(i & 127) * 4;
    int b = (int)(token >> 12);
    int k = (int)idx_f[token];
    float w0 = wsel[b * 2], w1v = wsel[b * 2 + 1];
    float4 xv = *(const float4*)(x + token * DDIM + d4);
    float4 cv = *(const float4*)(cb + (size_t)k * DDIM + d4);
    float4 mv = *(const float4*)(means + d4);
    float4 sv = *(const float4*)(stds + d4);
    float4 o;
#define COMPQ(f)                                                          \
    {                                                                     \
      float xx = xv.f;                                                    \
      float xc = fminf(fmaxf(xx, -1.f), 1.f);                             \
      float fi = rintf(__fdiv_rn(xc + 1.f, step));                        \
      float q  = __fadd_rn(__fmul_rn(fi, step), -1.f);                    \
      float qu = xx + (q - xx);                                           \
      float qk = __fadd_rn(__fmul_rn(cv.f, sv.f), mv.f);                  \
      float qks = xx + (qk - xx);                                         \
      o.f = w0 * qu + w1v * qks;                                          \
      float du = xx - q;  lu = fmaf(du, du, lu);                          \
      float dk = xx - qk; lk = fmaf(dk, dk, lk);                          \
    }
    COMPQ(x) COMPQ(y) COMPQ(z) COMPQ(w)
#undef COMPQ
    *(float4*)(out + token * DDIM + d4) = o;
  }
  // block loss reduction
  for (int m = 1; m <= 32; m <<= 1) {
    lu += __shfl_xor(lu, m, 64);
    lk += __shfl_xor(lk, m, 64);
  }
  __shared__ float slu[4], slk[4];
  int wid = tid >> 6, lane = tid & 63;
  if (lane == 0) { slu[wid] = lu; slk[wid] = lk; }
  __syncthreads();
  if (tid == 0) {
    atomicAdd(loss_acc + 0, slu[0] + slu[1] + slu[2] + slu[3]);
    atomicAdd(loss_acc + 1, slk[0] + slk[1] + slk[2] + slk[3]);
  }
}

__global__ void finalize_kernel(const float* __restrict__ ls, float* __restrict__ out_loss) {
  const float invN = 1.f / ((float)MTOK * (float)DDIM);  // 2^-25, exact
  out_loss[0] = 0.25f * (ls[0] * invN) + 0.25f * (ls[1] * invN);
}

extern "C" void kernel_launch(void* const* d_in, const int* in_sizes, int n_in,
                              void* d_out, int out_size, void* d_ws, size_t ws_size,
                              hipStream_t stream) {
  const float* x     = (const float*)d_in[0];
  const float* cb    = (const float*)d_in[1];
  const float* means = (const float*)d_in[2];
  const float* stds  = (const float*)d_in[3];
  const float* w1    = (const float*)d_in[4];
  const float* b1    = (const float*)d_in[5];
  const float* w2    = (const float*)d_in[6];
  const float* b2    = (const float*)d_in[7];
  float* out = (float*)d_out;
  float* ws  = (float*)d_ws;

  hipLaunchKernelGGL(init_ws, dim3(33), dim3(256), 0, stream, ws);
  hipLaunchKernelGGL(c2_kernel, dim3(NCODE), dim3(64), 0, stream, cb, ws + WS_C2);
  hipLaunchKernelGGL(pool_kernel, dim3(BB, 16), dim3(512), 0, stream, x, ws + WS_POOL);
  hipLaunchKernelGGL(selector_kernel, dim3(BB), dim3(256), 0, stream,
                     ws + WS_POOL, w1, b1, w2, b2, ws + WS_WGT, out);
  hipLaunchKernelGGL(gemm_argmin, dim3(MTOK / 64), dim3(256), 0, stream,
                     x, cb, means, stds, ws + WS_C2, out + IDX_OFF);
  hipLaunchKernelGGL(output_kernel, dim3(2048), dim3(256), 0, stream,
                     x, cb, means, stds, out + IDX_OFF, ws + WS_WGT, out, ws + WS_LOSS);
  hipLaunchKernelGGL(finalize_kernel, dim3(1), dim3(1), 0, stream,
                     ws + WS_LOSS, out + LOSS_OFF);
}